// Round 2
// baseline (473.427 us; speedup 1.0000x reference)
//
#include <hip/hip_runtime.h>

// LengthRegulator: B=32, T=1024, D=384, MAXLEN=8192 (fixed by harness).
// v6: output-centric expand. Scan kernel inverts cum into idx[B][ML]
// (source frame per output row, -1 in the zero tail; 1 MB scratch).
// Expand is then a PERFECT LINEAR SWEEP over the 402 MB output -- the
// exact access shape of the 6.3 TB/s fillBufferAligned on this buffer:
// each block owns 64 consecutive rows (96 KB contiguous), store address
// is pure induction (base + w*192 + t), no divergence, no imbalance,
// no runtime-dependent addressing on the store side, tail zeros fused.
// x reads are idx-gathered but L1/L3-resident (50 MB, ~7.5x reuse).
// Normal (cached) stores: v5's nontemporal stores slightly regressed.

#define B_    32
#define T_    1024
#define D_    384
#define ML_   8192
#define D4_   (D_ / 4)     // 96 float4 per row
#define NTHR  192          // 2 rows per store window, exactly 3 waves
#define R_    64           // output rows per expand block (96 KB)
#define NBLK  (ML_ / R_)   // 128 expand blocks per batch

typedef float f32x4 __attribute__((ext_vector_type(4)));

// --- Kernel 1: scan durations, invert cum -> per-output-row source idx ---
__global__ __launch_bounds__(T_) void lr_scan(const int* __restrict__ dur,
                                              int* __restrict__ idx,
                                              float* __restrict__ total_out) {
    const int b = blockIdx.x;
    const int t = threadIdx.x;
    const int lane = t & 63;
    const int wave = t >> 6;

    int d0 = dur[b * T_ + t];
    d0 = d0 > 0 ? d0 : 0;

    int v = d0;
    for (int off = 1; off < 64; off <<= 1) {
        int n = __shfl_up(v, off, 64);
        if (lane >= off) v += n;
    }

    __shared__ int wsum[16];
    if (lane == 63) wsum[wave] = v;
    __syncthreads();

    if (wave == 0 && lane < 16) {
        int w = wsum[lane];
        for (int off = 1; off < 16; off <<= 1) {
            int n = __shfl_up(w, off, 64);
            if (lane >= off) w += n;
        }
        wsum[lane] = w;
    }
    __syncthreads();

    const int c     = v + (wave > 0 ? wsum[wave - 1] : 0);  // inclusive cum
    const int total = wsum[15];
    if (t == T_ - 1) total_out[b] = (float)c;   // total <= 15360, exact fp32

    int* ib = idx + b * ML_;

    // Frame t owns output rows [c - d0, c), clipped to ML. Disjoint across
    // threads; adjacent threads write adjacent ranges -> decent coalescing.
    int e = c < ML_ ? c : ML_;
    int s = c - d0;
    if (s > ML_) s = ML_;
    for (int p = s; p < e; ++p) ib[p] = t;

    // Zero tail: rows [min(total,ML), ML) get idx = -1.
    const int tr = total < ML_ ? total : ML_;
    for (int p = tr + t; p < ML_; p += T_) ib[p] = -1;
}

// --- Kernel 2: linear-sweep expand ---------------------------------------
// grid = (NBLK, B_), 192 threads. Block owns rows [r0, r0+64) of batch b.
__global__ __launch_bounds__(NTHR) void lr_expand(const f32x4* __restrict__ x,
                                                  const int* __restrict__ idx,
                                                  f32x4* __restrict__ out) {
    const int b  = blockIdx.y;
    const int r0 = blockIdx.x * R_;
    const int t  = threadIdx.x;

    __shared__ int sidx[R_];
    if (t < R_) sidx[t] = idx[b * ML_ + r0 + t];
    __syncthreads();

    const int half = (t >= D4_) ? 1 : 0;        // which row of the window
    const int col  = t - half * D4_;            // 0..95, lane's column
    const f32x4* xb = x + (size_t)b * T_ * D4_;
    f32x4* ob = out + ((size_t)b * ML_ + r0) * D4_;

    // 32 window iterations: rows (2w, 2w+1). Store address is pure
    // induction: ob + w*192 + t -> each wave stores 1 KB contiguous,
    // block stores 96 KB contiguous, grid sweeps output linearly.
    #pragma unroll 8
    for (int w = 0; w < R_ / 2; ++w) {
        const int id = sidx[2 * w + half];
        f32x4 v = {0.f, 0.f, 0.f, 0.f};
        if (id >= 0) v = xb[(size_t)id * D4_ + col];
        ob[w * (2 * D4_) + t] = v;
    }
}

extern "C" void kernel_launch(void* const* d_in, const int* in_sizes, int n_in,
                              void* d_out, int out_size, void* d_ws, size_t ws_size,
                              hipStream_t stream) {
    const float* x   = (const float*)d_in[0];   // (B, T, D) fp32
    const int*   dur = (const int*)d_in[1];     // (B, T) int32
    // d_in[2] = max_len scalar (always 8192 here)

    float* out       = (float*)d_out;                   // (B, ML, D) fp32
    float* total_out = out + (size_t)B_ * ML_ * D_;     // (B,) as fp32
    int*   idx       = (int*)d_ws;                      // (B, ML) scratch, 1 MB

    lr_scan<<<B_, T_, 0, stream>>>(dur, idx, total_out);
    lr_expand<<<dim3(NBLK, B_), NTHR, 0, stream>>>(
        (const f32x4*)x, idx, (f32x4*)out);
}